// Round 1
// baseline (3827.822 us; speedup 1.0000x reference)
//
#include <hip/hip_runtime.h>
#include <math.h>
#include <float.h>

#define LNUM 4
#define BNUM 16
#define DNUM 768
#define P1   257
#define KPN  8
#define NK   2048
#define HW1  256
#define MID  128
#define MID2 64
#define HW2  1024
#define HW3  4096
#define IMG  224

// ---------------- workspace layout (float offsets) ----------------
constexpr size_t OFF_W23   = 0;                         // 512
constexpr size_t OFF_B23   = 512;                       // 2
constexpr size_t OFF_WT1   = 1024;                      // 9*768*128 = 884736
constexpr size_t OFF_WT2   = OFF_WT1 + 884736;          // 9*128*64  = 73728
constexpr size_t OFF_INVQ  = OFF_WT2 + 73728;           // 4*16*256  = 16384
constexpr size_t OFF_INVP  = OFF_INVQ + 16384;          // 4*16*2048 = 131072
constexpr size_t OFF_ALIGN = OFF_INVP + 131072;         // 16384
constexpr size_t OFF_IDX   = OFF_ALIGN + 16384;         // 16384 (int)
constexpr size_t OFF_PARTA = OFF_IDX + 16384;           // 4*768*16*2 = 98304
constexpr size_t OFF_SCA   = OFF_PARTA + 98304;         // 3072
constexpr size_t OFF_SHA   = OFF_SCA + 3072;            // 3072
constexpr size_t OFF_PART1 = OFF_SHA + 3072;            // 4*128*16*2 = 16384
constexpr size_t OFF_SC1   = OFF_PART1 + 16384;         // 512
constexpr size_t OFF_SH1   = OFF_SC1 + 512;             // 512
constexpr size_t OFF_PART2 = OFF_SH1 + 512;             // 4*64*64*2 = 32768
constexpr size_t OFF_SC2   = OFF_PART2 + 32768;         // 256
constexpr size_t OFF_SH2   = OFF_SC2 + 256;             // 256
constexpr size_t OFF_POOL  = OFF_SH2 + 256;             // 4*16*768 = 49152
constexpr size_t OFF_FUS   = OFF_POOL + 49152;          // 4*16*768*256 = 12582912
constexpr size_t OFF_C1O   = OFF_FUS + 12582912;        // 4*16*128*256 = 2097152
constexpr size_t OFF_H1    = OFF_C1O + 2097152;         // 4*16*128*1024 = 8388608
constexpr size_t OFF_C2O   = OFF_H1 + 8388608;          // 4*16*64*1024 = 4194304
constexpr size_t OFF_SM    = OFF_C2O + 4194304;         // 4*16*2*4096 = 524288
constexpr size_t WS_FLOATS = OFF_SM + 524288;           // ~116.5 MB

constexpr size_t OUT_LS  = 128;
constexpr size_t OUT_ASC = 128 + (size_t)LNUM*BNUM*2*IMG*IMG;

// ---------------- weight prep: transposes + deconv2*conv3 folding ----------------
__global__ void k_wprep(const float* __restrict__ c1w, const float* __restrict__ c2w,
                        const float* __restrict__ c3w, const float* __restrict__ c3b,
                        const float* __restrict__ ct2w, const float* __restrict__ ct2b,
                        float* __restrict__ ws) {
  int g = blockIdx.x * 256 + threadIdx.x;
  if (g < 884736) {
    // wt1[tap][ci][co] = conv1_w[co][ci][tap]
    int co = g & 127; int r = g >> 7; int ci = r % 768; int tap = r / 768;
    ws[OFF_WT1 + g] = c1w[((size_t)co * 768 + ci) * 9 + tap];
  } else if (g < 884736 + 73728) {
    int g2 = g - 884736;
    int co = g2 & 63; int r = g2 >> 6; int ci = r % 128; int tap = r / 128;
    ws[OFF_WT2 + g2] = c2w[((size_t)co * 128 + ci) * 9 + tap];
  } else if (g < 884736 + 73728 + 512) {
    // W23[c][c2][ab] = sum_o conv3_w[c2][o] * ct2_w[c][o][ab]
    int g3 = g - (884736 + 73728);
    int c = g3 >> 3, n = g3 & 7, c2 = n >> 2, ab = n & 3;
    float s = 0.f;
    for (int o = 0; o < 64; ++o) s += c3w[c2 * 64 + o] * ct2w[((size_t)c * 64 + o) * 4 + ab];
    ws[OFF_W23 + g3] = s;
  } else if (g < 884736 + 73728 + 514) {
    int c2 = g - (884736 + 73728 + 512);
    float s = c3b[c2];
    for (int o = 0; o < 64; ++o) s += c3w[c2 * 64 + o] * ct2b[o];
    ws[OFF_B23 + c2] = s;
  }
}

// ---------------- per-row inverse L2 norms ----------------
__global__ void k_rownorm(const float* __restrict__ qp, const float* __restrict__ pp,
                          float* __restrict__ inv_q, float* __restrict__ inv_p) {
  int wid = blockIdx.x * 4 + (threadIdx.x >> 6);
  int lane = threadIdx.x & 63;
  const int NQ = LNUM * BNUM * 256;
  const float* src; float* dst;
  if (wid < NQ) {
    int r = wid & 255, lb = wid >> 8;
    src = qp + ((size_t)lb * P1 + (r + 1)) * DNUM;
    dst = inv_q + wid;
  } else {
    int w2 = wid - NQ;
    int k = w2 & 2047, lb = w2 >> 11;
    int kp = k >> 8, r = k & 255;
    src = pp + (((size_t)lb * KPN + kp) * P1 + (r + 1)) * DNUM;
    dst = inv_p + w2;
  }
  float ss = 0.f;
  const float4* s4 = (const float4*)src;
  for (int i = lane; i < DNUM / 4; i += 64) {
    float4 v = s4[i];
    ss += v.x * v.x + v.y * v.y + v.z * v.z + v.w * v.w;
  }
  #pragma unroll
  for (int o = 32; o; o >>= 1) ss += __shfl_down(ss, o);
  if (lane == 0) {
    float n = fmaxf(sqrtf(ss), 1e-12f);
    *dst = 1.f / n;
  }
}

// ---------------- fused cost GEMM + min/argmin ----------------
// block: (qt, b, l); 32 q rows x all 2048 k. 256 thr = 8 tq x 32 tk; thread tile 4q x 8k.
__global__ __launch_bounds__(256) void k_cost(
    const float* __restrict__ qp, const float* __restrict__ pp,
    const float* __restrict__ inv_q, const float* __restrict__ inv_p,
    float* __restrict__ align_out, int* __restrict__ idx_out) {
  __shared__ float qs[32 * 32];
  __shared__ float ps[256 * 32];
  __shared__ float redv[32][33];
  __shared__ int   redi[32][33];
  int qt = blockIdx.x, b = blockIdx.y, l = blockIdx.z;
  int lb = l * BNUM + b;
  int t = threadIdx.x;
  int tq = t >> 5, tk = t & 31;
  const float* qbase = qp + ((size_t)lb * P1 + 1 + qt * 32) * DNUM;

  float rb[4]; int ri[4];
  #pragma unroll
  for (int i = 0; i < 4; ++i) { rb[i] = -FLT_MAX; ri[i] = 0; }

  for (int kt = 0; kt < NK; kt += 256) {
    float acc[4][8];
    #pragma unroll
    for (int i = 0; i < 4; ++i)
      #pragma unroll
      for (int j = 0; j < 8; ++j) acc[i][j] = 0.f;

    for (int kc = 0; kc < DNUM; kc += 32) {
      { // stage q 32x32
        int r = t >> 3, c4 = t & 7;
        float4 v = *(const float4*)(qbase + (size_t)r * DNUM + kc + c4 * 4);
        *(float4*)(qs + r * 32 + c4 * 4) = v;
      }
      // stage p 256x32, XOR-swizzled
      #pragma unroll
      for (int it = 0; it < 8; ++it) {
        int r = it * 32 + (t >> 3), c4 = t & 7;
        int k = kt + r;
        const float* prow = pp + (((size_t)lb * KPN + (k >> 8)) * P1 + 1 + (k & 255)) * DNUM;
        float4 v = *(const float4*)(prow + kc + c4 * 4);
        *(float4*)(ps + r * 32 + ((c4 ^ (r & 7)) << 2)) = v;
      }
      __syncthreads();
      #pragma unroll
      for (int kk4 = 0; kk4 < 8; ++kk4) {
        float4 qv[4];
        #pragma unroll
        for (int i = 0; i < 4; ++i)
          qv[i] = *(const float4*)(qs + (tq * 4 + i) * 32 + kk4 * 4);
        #pragma unroll
        for (int j = 0; j < 8; ++j) {
          int r = tk + 32 * j;
          float4 pv = *(const float4*)(ps + r * 32 + ((kk4 ^ (r & 7)) << 2));
          #pragma unroll
          for (int i = 0; i < 4; ++i) {
            acc[i][j] += qv[i].x * pv.x;
            acc[i][j] += qv[i].y * pv.y;
            acc[i][j] += qv[i].z * pv.z;
            acc[i][j] += qv[i].w * pv.w;
          }
        }
      }
      __syncthreads();
    }
    // fold into running best (sim = dot * inv_p; inv_q applied at the end)
    #pragma unroll
    for (int j = 0; j < 8; ++j) {
      int k = kt + tk + 32 * j;
      float ip = inv_p[(size_t)lb * NK + k];
      #pragma unroll
      for (int i = 0; i < 4; ++i) {
        float v = acc[i][j] * ip;
        if (v > rb[i]) { rb[i] = v; ri[i] = k; }
      }
    }
  }
  #pragma unroll
  for (int i = 0; i < 4; ++i) { redv[tq * 4 + i][tk] = rb[i]; redi[tq * 4 + i][tk] = ri[i]; }
  __syncthreads();
  if (t < 32) {
    float bv = redv[t][0]; int bi = redi[t][0];
    for (int j = 1; j < 32; ++j) {
      float v = redv[t][j]; int ii = redi[t][j];
      if (v > bv || (v == bv && ii < bi)) { bv = v; bi = ii; }
    }
    int q = qt * 32 + t;
    float iq = inv_q[(size_t)lb * HW1 + q];
    align_out[(size_t)lb * HW1 + q] = 1.f - iq * bv;
    idx_out[(size_t)lb * HW1 + q] = bi;
  }
}

// ---------------- fusion = q_n + |q_n - aligned_n|, NCHW, + BN partial sums ----------------
__global__ void k_fusion(const float* __restrict__ qp, const float* __restrict__ pp,
                         const float* __restrict__ inv_q, const float* __restrict__ inv_p,
                         const int* __restrict__ idx_ws, float* __restrict__ fus,
                         float* __restrict__ partA) {
  __shared__ float tile[32][37];
  __shared__ float s_iq[HW1], s_ip[HW1];
  __shared__ int   s_id[HW1];
  int b = blockIdx.x, l = blockIdx.y;
  int lb = l * BNUM + b;
  int t = threadIdx.x;
  s_iq[t] = inv_q[(size_t)lb * HW1 + t];
  int id0 = idx_ws[(size_t)lb * HW1 + t];
  s_id[t] = id0;
  s_ip[t] = inv_p[(size_t)lb * NK + id0];
  __syncthreads();
  int hi = t >> 3, c4 = t & 7;   // phase A: 32 hw x 8 float4 (32 d)
  int di = t >> 3, h4 = t & 7;   // phase B: 32 d x 8 float4 (32 hw)
  for (int dc = 0; dc < DNUM; dc += 32) {
    float s = 0.f, ss = 0.f;
    for (int hb = 0; hb < HW1; hb += 32) {
      { // phase A
        int hw = hb + hi;
        const float* qrow = qp + ((size_t)lb * P1 + 1 + hw) * DNUM + dc;
        int ii = s_id[hw];
        const float* prow = pp + (((size_t)lb * KPN + (ii >> 8)) * P1 + 1 + (ii & 255)) * DNUM + dc;
        float iq = s_iq[hw], ip = s_ip[hw];
        float4 qv = *(const float4*)(qrow + c4 * 4);
        float4 pv = *(const float4*)(prow + c4 * 4);
        float f0 = qv.x * iq; f0 = f0 + fabsf(f0 - pv.x * ip);
        float f1 = qv.y * iq; f1 = f1 + fabsf(f1 - pv.y * ip);
        float f2 = qv.z * iq; f2 = f2 + fabsf(f2 - pv.z * ip);
        float f3 = qv.w * iq; f3 = f3 + fabsf(f3 - pv.w * ip);
        tile[hi][c4 * 4 + 0] = f0; tile[hi][c4 * 4 + 1] = f1;
        tile[hi][c4 * 4 + 2] = f2; tile[hi][c4 * 4 + 3] = f3;
      }
      __syncthreads();
      { // phase B (transposed write, coalesced over hw)
        float v0 = tile[h4 * 4 + 0][di];
        float v1 = tile[h4 * 4 + 1][di];
        float v2 = tile[h4 * 4 + 2][di];
        float v3 = tile[h4 * 4 + 3][di];
        float4 o; o.x = v0; o.y = v1; o.z = v2; o.w = v3;
        *(float4*)(fus + ((size_t)lb * DNUM + dc + di) * HW1 + hb + h4 * 4) = o;
        s += v0 + v1 + v2 + v3;
        ss += v0 * v0 + v1 * v1 + v2 * v2 + v3 * v3;
      }
      __syncthreads();
    }
    #pragma unroll
    for (int o = 4; o; o >>= 1) { s += __shfl_down(s, o, 8); ss += __shfl_down(ss, o, 8); }
    if (h4 == 0) {
      int d = dc + di;
      partA[(((size_t)l * DNUM + d) * BNUM + b) * 2 + 0] = s;
      partA[(((size_t)l * DNUM + d) * BNUM + b) * 2 + 1] = ss;
    }
  }
}

// ---------------- BN stats finalize: parts[l][C][nparts][2] -> scale/shift[l][C] ----------------
__global__ void k_bn_final(const float* __restrict__ part, int nparts, int C, float cnt,
                           const float* __restrict__ gamma, const float* __restrict__ beta,
                           int per_layer_gb, float* __restrict__ scale, float* __restrict__ shift) {
  int i = blockIdx.x * 256 + threadIdx.x;
  if (i >= LNUM * C) return;
  int c = i % C;
  float s = 0.f, ss = 0.f;
  const float* p = part + (size_t)i * nparts * 2;
  for (int j = 0; j < nparts; ++j) { s += p[j * 2]; ss += p[j * 2 + 1]; }
  float mean = s / cnt, var = ss / cnt - mean * mean;
  float g = gamma[per_layer_gb ? i : c], bb = beta[per_layer_gb ? i : c];
  float sc = g * rsqrtf(var + 1e-5f);
  scale[i] = sc; shift[i] = bb - mean * sc;
}

// ---------------- conv1: 768->128 3x3 SAME on 16x16, BN-A applied on load ----------------
__global__ __launch_bounds__(256) void k_conv1(
    const float* __restrict__ fus, const float* __restrict__ scA, const float* __restrict__ shA,
    const float* __restrict__ wt1, float* __restrict__ out1, float* __restrict__ part1) {
  __shared__ float ins[32 * 256];
  __shared__ float wsm[32 * 32];
  int cog = blockIdx.x, b = blockIdx.y, l = blockIdx.z;
  int lb = l * BNUM + b;
  int t = threadIdx.x;
  int tco = t >> 5, tpos = t & 31;
  const float* fin = fus + (size_t)lb * DNUM * HW1;
  float acc[4][8];
  #pragma unroll
  for (int i = 0; i < 4; ++i)
    #pragma unroll
    for (int j = 0; j < 8; ++j) acc[i][j] = 0.f;

  int p0 = t;
  for (int tap = 0; tap < 9; ++tap) {
    int ky = tap / 3 - 1, kx = tap % 3 - 1;
    int y = (p0 >> 4) + ky, x = (p0 & 15) + kx;
    bool valid = ((unsigned)y < 16u) && ((unsigned)x < 16u);
    int yx = y * 16 + x;
    for (int cc = 0; cc < DNUM; cc += 32) {
      for (int ci = 0; ci < 32; ++ci) {
        int c = cc + ci;
        float v = 0.f;
        if (valid) v = fin[(size_t)c * HW1 + yx] * scA[l * DNUM + c] + shA[l * DNUM + c];
        ins[ci * HW1 + p0] = v;
      }
      {
        int ci = t >> 3, c4 = t & 7;
        *(float4*)(wsm + ci * 32 + c4 * 4) =
            *(const float4*)(wt1 + ((size_t)tap * DNUM + cc + ci) * MID + cog * 32 + c4 * 4);
      }
      __syncthreads();
      #pragma unroll
      for (int ci = 0; ci < 32; ++ci) {
        float4 wv = *(const float4*)(wsm + ci * 32 + tco * 4);
        float4 x0 = *(const float4*)(ins + ci * HW1 + tpos * 8);
        float4 x1 = *(const float4*)(ins + ci * HW1 + tpos * 8 + 4);
        float wa[4] = {wv.x, wv.y, wv.z, wv.w};
        float xa[8] = {x0.x, x0.y, x0.z, x0.w, x1.x, x1.y, x1.z, x1.w};
        #pragma unroll
        for (int i = 0; i < 4; ++i)
          #pragma unroll
          for (int j = 0; j < 8; ++j) acc[i][j] += wa[i] * xa[j];
      }
      __syncthreads();
    }
  }
  int co0 = cog * 32 + tco * 4;
  #pragma unroll
  for (int i = 0; i < 4; ++i) {
    float s = 0.f, ssum = 0.f;
    #pragma unroll
    for (int j = 0; j < 8; ++j) { s += acc[i][j]; ssum += acc[i][j] * acc[i][j]; }
    #pragma unroll
    for (int o = 16; o; o >>= 1) { s += __shfl_down(s, o, 32); ssum += __shfl_down(ssum, o, 32); }
    if (tpos == 0) {
      part1[(((size_t)l * MID + co0 + i) * BNUM + b) * 2 + 0] = s;
      part1[(((size_t)l * MID + co0 + i) * BNUM + b) * 2 + 1] = ssum;
    }
    float4 o0, o1;
    o0.x = acc[i][0]; o0.y = acc[i][1]; o0.z = acc[i][2]; o0.w = acc[i][3];
    o1.x = acc[i][4]; o1.y = acc[i][5]; o1.z = acc[i][6]; o1.w = acc[i][7];
    *(float4*)(out1 + ((size_t)lb * MID + co0 + i) * HW1 + tpos * 8) = o0;
    *(float4*)(out1 + ((size_t)lb * MID + co0 + i) * HW1 + tpos * 8 + 4) = o1;
  }
}

// ---------------- deconv1 (ct1): GEMM over n = o*4+ab, bn1+relu applied on load ----------------
__global__ __launch_bounds__(256) void k_deconv1(
    const float* __restrict__ out1, const float* __restrict__ sc1, const float* __restrict__ sh1,
    const float* __restrict__ ct1w, const float* __restrict__ ct1b, float* __restrict__ h1) {
  __shared__ float xs[32 * 64];
  __shared__ float wds[32 * 64];
  int ng = blockIdx.x >> 2, pg = blockIdx.x & 3;
  int b = blockIdx.y, l = blockIdx.z;
  int lb = l * BNUM + b;
  int t = threadIdx.x;
  int tn = t >> 4, tp = t & 15;
  float acc[4][4];
  #pragma unroll
  for (int i = 0; i < 4; ++i)
    #pragma unroll
    for (int j = 0; j < 4; ++j) acc[i][j] = 0.f;

  for (int cc = 0; cc < MID; cc += 32) {
    #pragma unroll
    for (int it = 0; it < 8; ++it) {
      int ii = it * 256 + t;
      int ci = ii >> 6, p = ii & 63;
      int c = cc + ci;
      float raw = out1[((size_t)lb * MID + c) * HW1 + pg * 64 + p];
      xs[ci * 64 + p] = fmaxf(raw * sc1[l * MID + c] + sh1[l * MID + c], 0.f);
    }
    #pragma unroll
    for (int it = 0; it < 2; ++it) {
      int ii = it * 256 + t;
      int ci = ii >> 4, n4 = ii & 15;
      *(float4*)(wds + ci * 64 + n4 * 4) =
          *(const float4*)(ct1w + ((size_t)(cc + ci)) * 512 + ng * 64 + n4 * 4);
    }
    __syncthreads();
    #pragma unroll
    for (int ci = 0; ci < 32; ++ci) {
      float4 wv = *(const float4*)(wds + ci * 64 + tn * 4);
      float4 xv = *(const float4*)(xs + ci * 64 + tp * 4);
      float wa[4] = {wv.x, wv.y, wv.z, wv.w};
      float xa[4] = {xv.x, xv.y, xv.z, xv.w};
      #pragma unroll
      for (int i = 0; i < 4; ++i)
        #pragma unroll
        for (int j = 0; j < 4; ++j) acc[i][j] += wa[i] * xa[j];
    }
    __syncthreads();
  }
  #pragma unroll
  for (int i = 0; i < 4; ++i) {
    int n = ng * 64 + tn * 4 + i;
    int o = n >> 2, ab = n & 3, a = ab >> 1, bb = ab & 1;
    float bias = ct1b[o];
    #pragma unroll
    for (int j = 0; j < 4; ++j) {
      int p = pg * 64 + tp * 4 + j;
      int y = p >> 4, x = p & 15;
      h1[((size_t)lb * MID + o) * HW2 + (2 * y + a) * 32 + (2 * x + bb)] = acc[i][j] + bias;
    }
  }
}

// ---------------- conv2: 128->64 3x3 SAME on 32x32 ----------------
__global__ __launch_bounds__(256) void k_conv2(
    const float* __restrict__ h1, const float* __restrict__ wt2,
    float* __restrict__ out2, float* __restrict__ part2) {
  __shared__ float ins[32 * 256];
  __shared__ float wsm[32 * 32];
  int cog = blockIdx.x >> 2, posg = blockIdx.x & 3;
  int b = blockIdx.y, l = blockIdx.z;
  int lb = l * BNUM + b;
  int t = threadIdx.x;
  int tco = t >> 5, tpos = t & 31;
  const float* fin = h1 + (size_t)lb * MID * HW2;
  float acc[4][8];
  #pragma unroll
  for (int i = 0; i < 4; ++i)
    #pragma unroll
    for (int j = 0; j < 8; ++j) acc[i][j] = 0.f;

  int gp = posg * 256 + t;
  int y0 = gp >> 5, x0 = gp & 31;
  for (int tap = 0; tap < 9; ++tap) {
    int ky = tap / 3 - 1, kx = tap % 3 - 1;
    int y = y0 + ky, x = x0 + kx;
    bool valid = ((unsigned)y < 32u) && ((unsigned)x < 32u);
    int yx = y * 32 + x;
    for (int cc = 0; cc < MID; cc += 32) {
      for (int ci = 0; ci < 32; ++ci) {
        float v = valid ? fin[(size_t)(cc + ci) * HW2 + yx] : 0.f;
        ins[ci * HW1 + t] = v;
      }
      {
        int ci = t >> 3, c4 = t & 7;
        *(float4*)(wsm + ci * 32 + c4 * 4) =
            *(const float4*)(wt2 + ((size_t)tap * MID + cc + ci) * MID2 + cog * 32 + c4 * 4);
      }
      __syncthreads();
      #pragma unroll
      for (int ci = 0; ci < 32; ++ci) {
        float4 wv = *(const float4*)(wsm + ci * 32 + tco * 4);
        float4 v0 = *(const float4*)(ins + ci * HW1 + tpos * 8);
        float4 v1 = *(const float4*)(ins + ci * HW1 + tpos * 8 + 4);
        float wa[4] = {wv.x, wv.y, wv.z, wv.w};
        float xa[8] = {v0.x, v0.y, v0.z, v0.w, v1.x, v1.y, v1.z, v1.w};
        #pragma unroll
        for (int i = 0; i < 4; ++i)
          #pragma unroll
          for (int j = 0; j < 8; ++j) acc[i][j] += wa[i] * xa[j];
      }
      __syncthreads();
    }
  }
  int co0 = cog * 32 + tco * 4;
  #pragma unroll
  for (int i = 0; i < 4; ++i) {
    float s = 0.f, ssum = 0.f;
    #pragma unroll
    for (int j = 0; j < 8; ++j) { s += acc[i][j]; ssum += acc[i][j] * acc[i][j]; }
    #pragma unroll
    for (int o = 16; o; o >>= 1) { s += __shfl_down(s, o, 32); ssum += __shfl_down(ssum, o, 32); }
    if (tpos == 0) {
      part2[(((size_t)l * MID2 + co0 + i) * 64 + (b * 4 + posg)) * 2 + 0] = s;
      part2[(((size_t)l * MID2 + co0 + i) * 64 + (b * 4 + posg)) * 2 + 1] = ssum;
    }
    float4 o0, o1;
    o0.x = acc[i][0]; o0.y = acc[i][1]; o0.z = acc[i][2]; o0.w = acc[i][3];
    o1.x = acc[i][4]; o1.y = acc[i][5]; o1.z = acc[i][6]; o1.w = acc[i][7];
    *(float4*)(out2 + ((size_t)lb * MID2 + co0 + i) * HW2 + posg * 256 + tpos * 8) = o0;
    *(float4*)(out2 + ((size_t)lb * MID2 + co0 + i) * HW2 + posg * 256 + tpos * 8 + 4) = o1;
  }
}

// ---------------- fused deconv2+conv3+softmax (bn2+relu on load) ----------------
__global__ void k_dc2c3sm(const float* __restrict__ out2, const float* __restrict__ sc2,
                          const float* __restrict__ sh2, const float* __restrict__ wsW23,
                          const float* __restrict__ wsB23, float* __restrict__ sm) {
  __shared__ float w23[64 * 8];
  __shared__ float b23s[2];
  __shared__ float ssc[64], ssh[64];
  int b = blockIdx.x, l = blockIdx.y;
  int lb = l * BNUM + b;
  int t = threadIdx.x;
  w23[t] = wsW23[t];
  w23[t + 256] = wsW23[t + 256];
  if (t < 2) b23s[t] = wsB23[t];
  if (t < 64) { ssc[t] = sc2[l * MID2 + t]; ssh[t] = sh2[l * MID2 + t]; }
  __syncthreads();
  for (int it = 0; it < 4; ++it) {
    int p = it * 256 + t;
    float a[8];
    #pragma unroll
    for (int n = 0; n < 8; ++n) a[n] = 0.f;
    for (int c = 0; c < 64; ++c) {
      float v = fmaxf(out2[((size_t)lb * MID2 + c) * HW2 + p] * ssc[c] + ssh[c], 0.f);
      #pragma unroll
      for (int n = 0; n < 8; ++n) a[n] += v * w23[c * 8 + n];
    }
    int y = p >> 5, x = p & 31;
    #pragma unroll
    for (int ab = 0; ab < 4; ++ab) {
      float v0 = a[ab] + b23s[0];
      float v1 = a[4 + ab] + b23s[1];
      float m = fmaxf(v0, v1);
      float e0 = expf(v0 - m), e1 = expf(v1 - m);
      float inv = 1.f / (e0 + e1);
      int aa = ab >> 1, bb = ab & 1;
      int op = (2 * y + aa) * 64 + 2 * x + bb;
      sm[((size_t)lb * 2 + 0) * HW3 + op] = e0 * inv;
      sm[((size_t)lb * 2 + 1) * HW3 + op] = e1 * inv;
    }
  }
}

// ---------------- bilinear resize SxS -> 224x224 (jax half-pixel + edge renorm semantics) ----------------
template <int S>
__global__ void k_resize(const float* __restrict__ in, float* __restrict__ out, int total) {
  int gid = blockIdx.x * 256 + threadIdx.x;
  if (gid >= total) return;
  int m = gid / (IMG * IMG);
  int r = gid - m * (IMG * IMG);
  int oy = r / IMG, ox = r - oy * IMG;
  const float scale = (float)S / (float)IMG;
  float fy = ((float)oy + 0.5f) * scale - 0.5f;
  float fx = ((float)ox + 0.5f) * scale - 0.5f;
  float y0f = floorf(fy), x0f = floorf(fx);
  float wy = fy - y0f, wx = fx - x0f;
  int y0 = (int)y0f, x0 = (int)x0f;
  int y1 = y0 + 1, x1 = x0 + 1;
  y0 = min(max(y0, 0), S - 1); y1 = min(max(y1, 0), S - 1);
  x0 = min(max(x0, 0), S - 1); x1 = min(max(x1, 0), S - 1);
  const float* src = in + (size_t)m * S * S;
  float v00 = src[y0 * S + x0], v01 = src[y0 * S + x1];
  float v10 = src[y1 * S + x0], v11 = src[y1 * S + x1];
  out[gid] = (1.f - wy) * ((1.f - wx) * v00 + wx * v01) + wy * ((1.f - wx) * v10 + wx * v11);
}

// ---------------- pooled = (mean + top10mean)/2 over post-BN fusion rows ----------------
__global__ void k_pooled(const float* __restrict__ fus, const float* __restrict__ scA,
                         const float* __restrict__ shA, float* __restrict__ pooled) {
  int gid = blockIdx.x * 256 + threadIdx.x;
  if (gid >= LNUM * BNUM * DNUM) return;
  int lb = gid / DNUM, d = gid - lb * DNUM;
  int l = lb >> 4;
  float sc = scA[l * DNUM + d], sh = shA[l * DNUM + d];
  const float4* row = (const float4*)(fus + (size_t)gid * HW1);
  float top[10];
  #pragma unroll
  for (int i = 0; i < 10; ++i) top[i] = -FLT_MAX;
  float sum = 0.f;
  for (int c = 0; c < HW1 / 4; ++c) {
    float4 v4 = row[c];
    float vals[4] = {v4.x, v4.y, v4.z, v4.w};
    #pragma unroll
    for (int u = 0; u < 4; ++u) {
      float v = vals[u] * sc + sh;
      sum += v;
      if (v > top[9]) {
        top[9] = v;
        #pragma unroll
        for (int q = 9; q > 0; --q) {
          if (top[q] > top[q - 1]) { float tmp = top[q - 1]; top[q - 1] = top[q]; top[q] = tmp; }
        }
      }
    }
  }
  float t10 = 0.f;
  #pragma unroll
  for (int i = 0; i < 10; ++i) t10 += top[i];
  pooled[gid] = 0.5f * (sum * (1.f / 256.f) + t10 * 0.1f);
}

// ---------------- global head: g1(+bn,relu) -> g2(+bn,relu) -> g3; one block per layer ----------------
__global__ void k_head(const float* __restrict__ pooled,
                       const float* __restrict__ g1w, const float* __restrict__ gbn1g,
                       const float* __restrict__ gbn1b, const float* __restrict__ g2w,
                       const float* __restrict__ gbn2g, const float* __restrict__ gbn2b,
                       const float* __restrict__ g3w, float* __restrict__ outgl) {
  __shared__ float g1o[16 * 128];
  __shared__ float g2o[16 * 64];
  __shared__ float ssc[128], ssh[128];
  int l = blockIdx.x;
  int t = threadIdx.x;
  const float* pl = pooled + (size_t)l * BNUM * DNUM;
  for (int it = 0; it < 8; ++it) {
    int id = it * 256 + t;
    int b = id >> 7, j = id & 127;
    const float* pr = pl + (size_t)b * DNUM;
    const float* wr = g1w + (size_t)j * DNUM;
    float s = 0.f;
    for (int k = 0; k < DNUM; k += 4)
      s += pr[k] * wr[k] + pr[k + 1] * wr[k + 1] + pr[k + 2] * wr[k + 2] + pr[k + 3] * wr[k + 3];
    g1o[b * 128 + j] = s;
  }
  __syncthreads();
  if (t < 128) {
    float s = 0.f, ss = 0.f;
    for (int b = 0; b < 16; ++b) { float v = g1o[b * 128 + t]; s += v; ss += v * v; }
    float m = s * (1.f / 16.f), var = ss * (1.f / 16.f) - m * m;
    float sc = gbn1g[t] * rsqrtf(var + 1e-5f);
    ssc[t] = sc; ssh[t] = gbn1b[t] - m * sc;
  }
  __syncthreads();
  for (int it = 0; it < 8; ++it) {
    int id = it * 256 + t;
    int b = id >> 7, j = id & 127;
    g1o[b * 128 + j] = fmaxf(g1o[b * 128 + j] * ssc[j] + ssh[j], 0.f);
  }
  __syncthreads();
  for (int it = 0; it < 4; ++it) {
    int id = it * 256 + t;
    int b = id >> 6, j = id & 63;
    const float* wr = g2w + (size_t)j * 128;
    float s = 0.f;
    for (int k = 0; k < 128; ++k) s += g1o[b * 128 + k] * wr[k];
    g2o[b * 64 + j] = s;
  }
  __syncthreads();
  if (t < 64) {
    float s = 0.f, ss = 0.f;
    for (int b = 0; b < 16; ++b) { float v = g2o[b * 64 + t]; s += v; ss += v * v; }
    float m = s * (1.f / 16.f), var = ss * (1.f / 16.f) - m * m;
    float sc = gbn2g[t] * rsqrtf(var + 1e-5f);
    ssc[t] = sc; ssh[t] = gbn2b[t] - m * sc;
  }
  __syncthreads();
  for (int it = 0; it < 4; ++it) {
    int id = it * 256 + t;
    int b = id >> 6, j = id & 63;
    g2o[b * 64 + j] = fmaxf(g2o[b * 64 + j] * ssc[j] + ssh[j], 0.f);
  }
  __syncthreads();
  if (t < 32) {
    int b = t >> 1, c = t & 1;
    const float* wr = g3w + (size_t)c * 64;
    float s = 0.f;
    for (int k = 0; k < 64; ++k) s += g2o[b * 64 + k] * wr[k];
    outgl[((size_t)l * BNUM + b) * 2 + c] = s;
  }
}

// ---------------- launch ----------------
extern "C" void kernel_launch(void* const* d_in, const int* in_sizes, int n_in,
                              void* d_out, int out_size, void* d_ws, size_t ws_size,
                              hipStream_t stream) {
  (void)in_sizes; (void)n_in; (void)out_size;
  if (ws_size < WS_FLOATS * sizeof(float)) return;  // workspace too small: fail loudly via mismatch

  const float* qp    = (const float*)d_in[1];
  const float* pp    = (const float*)d_in[3];
  const float* sbg   = (const float*)d_in[4];
  const float* sbb   = (const float*)d_in[5];
  const float* c1w   = (const float*)d_in[6];
  const float* bn1g  = (const float*)d_in[7];
  const float* bn1b  = (const float*)d_in[8];
  const float* ct1w  = (const float*)d_in[9];
  const float* ct1b  = (const float*)d_in[10];
  const float* c2w   = (const float*)d_in[11];
  const float* bn2g  = (const float*)d_in[12];
  const float* bn2b  = (const float*)d_in[13];
  const float* ct2w  = (const float*)d_in[14];
  const float* ct2b  = (const float*)d_in[15];
  const float* c3w   = (const float*)d_in[16];
  const float* c3b   = (const float*)d_in[17];
  const float* g1w   = (const float*)d_in[18];
  const float* gbn1g = (const float*)d_in[19];
  const float* gbn1b = (const float*)d_in[20];
  const float* g2w   = (const float*)d_in[21];
  const float* gbn2g = (const float*)d_in[22];
  const float* gbn2b = (const float*)d_in[23];
  const float* g3w   = (const float*)d_in[24];

  float* ws = (float*)d_ws;
  float* out = (float*)d_out;

  float* invq  = ws + OFF_INVQ;
  float* invp  = ws + OFF_INVP;
  float* alignb = ws + OFF_ALIGN;
  int*   idxb  = (int*)(ws + OFF_IDX);
  float* partA = ws + OFF_PARTA;
  float* scA   = ws + OFF_SCA;
  float* shA   = ws + OFF_SHA;
  float* part1 = ws + OFF_PART1;
  float* sc1   = ws + OFF_SC1;
  float* sh1   = ws + OFF_SH1;
  float* part2 = ws + OFF_PART2;
  float* sc2   = ws + OFF_SC2;
  float* sh2   = ws + OFF_SH2;
  float* poolb = ws + OFF_POOL;
  float* fusb  = ws + OFF_FUS;
  float* c1o   = ws + OFF_C1O;
  float* h1b   = ws + OFF_H1;
  float* c2o   = ws + OFF_C2O;
  float* smb   = ws + OFF_SM;
  float* wt1   = ws + OFF_WT1;
  float* wt2   = ws + OFF_WT2;

  k_wprep<<<(884736 + 73728 + 514 + 255) / 256, 256, 0, stream>>>(c1w, c2w, c3w, c3b, ct2w, ct2b, ws);
  k_rownorm<<<(LNUM * BNUM * (256 + 2048)) / 4, 256, 0, stream>>>(qp, pp, invq, invp);
  k_cost<<<dim3(8, BNUM, LNUM), 256, 0, stream>>>(qp, pp, invq, invp, alignb, idxb);
  k_fusion<<<dim3(BNUM, LNUM), 256, 0, stream>>>(qp, pp, invq, invp, idxb, fusb, partA);
  k_bn_final<<<(LNUM * DNUM + 255) / 256, 256, 0, stream>>>(partA, 16, DNUM, 4096.f, sbg, sbb, 1, scA, shA);
  k_conv1<<<dim3(4, BNUM, LNUM), 256, 0, stream>>>(fusb, scA, shA, wt1, c1o, part1);
  k_bn_final<<<(LNUM * MID + 255) / 256, 256, 0, stream>>>(part1, 16, MID, 4096.f, bn1g, bn1b, 0, sc1, sh1);
  k_deconv1<<<dim3(32, BNUM, LNUM), 256, 0, stream>>>(c1o, sc1, sh1, ct1w, ct1b, h1b);
  k_conv2<<<dim3(8, BNUM, LNUM), 256, 0, stream>>>(h1b, wt2, c2o, part2);
  k_bn_final<<<(LNUM * MID2 + 255) / 256, 256, 0, stream>>>(part2, 64, MID2, 16384.f, bn2g, bn2b, 0, sc2, sh2);
  k_dc2c3sm<<<dim3(BNUM, LNUM), 256, 0, stream>>>(c2o, sc2, sh2, ws + OFF_W23, ws + OFF_B23, smb);
  k_resize<64><<<(LNUM * BNUM * 2 * IMG * IMG + 255) / 256, 256, 0, stream>>>(smb, out + OUT_LS, LNUM * BNUM * 2 * IMG * IMG);
  k_resize<16><<<(LNUM * BNUM * IMG * IMG + 255) / 256, 256, 0, stream>>>(alignb, out + OUT_ASC, LNUM * BNUM * IMG * IMG);
  k_pooled<<<(LNUM * BNUM * DNUM + 255) / 256, 256, 0, stream>>>(fusb, scA, shA, poolb);
  k_head<<<LNUM, 256, 0, stream>>>(poolb, g1w, gbn1g, gbn1b, g2w, gbn2g, gbn2b, g3w, out);
}

// Round 2
// 2990.760 us; speedup vs baseline: 1.2799x; 1.2799x over previous
//
#include <hip/hip_runtime.h>
#include <math.h>
#include <float.h>

#define LNUM 4
#define BNUM 16
#define DNUM 768
#define P1   257
#define KPN  8
#define NK   2048
#define HW1  256
#define MID  128
#define MID2 64
#define HW2  1024
#define HW3  4096
#define IMG  224

// ---------------- workspace layout (float offsets) ----------------
constexpr size_t OFF_W23   = 0;                         // 512
constexpr size_t OFF_B23   = 512;                       // 2
constexpr size_t OFF_WT1   = 1024;                      // 9*768*128 = 884736
constexpr size_t OFF_WT2   = OFF_WT1 + 884736;          // 9*128*64  = 73728
constexpr size_t OFF_INVQ  = OFF_WT2 + 73728;           // 4*16*256  = 16384
constexpr size_t OFF_INVP  = OFF_INVQ + 16384;          // 4*16*2048 = 131072
constexpr size_t OFF_ALIGN = OFF_INVP + 131072;         // 16384
constexpr size_t OFF_IDX   = OFF_ALIGN + 16384;         // 16384 (int)
constexpr size_t OFF_PARTA = OFF_IDX + 16384;           // 4*768*16*2 = 98304
constexpr size_t OFF_SCA   = OFF_PARTA + 98304;         // 3072
constexpr size_t OFF_SHA   = OFF_SCA + 3072;            // 3072
constexpr size_t OFF_PART1 = OFF_SHA + 3072;            // 4*128*16*2 = 16384
constexpr size_t OFF_SC1   = OFF_PART1 + 16384;         // 512
constexpr size_t OFF_SH1   = OFF_SC1 + 512;             // 512
constexpr size_t OFF_PART2 = OFF_SH1 + 512;             // 4*64*64*2 = 32768
constexpr size_t OFF_SC2   = OFF_PART2 + 32768;         // 256
constexpr size_t OFF_SH2   = OFF_SC2 + 256;             // 256
constexpr size_t OFF_POOL  = OFF_SH2 + 256;             // 4*16*768 = 49152
constexpr size_t OFF_FUS   = OFF_POOL + 49152;          // 4*16*768*256 = 12582912
constexpr size_t OFF_C1O   = OFF_FUS + 12582912;        // 4*16*128*256 = 2097152
constexpr size_t OFF_H1    = OFF_C1O + 2097152;         // 4*16*128*1024 = 8388608
constexpr size_t OFF_C2O   = OFF_H1 + 8388608;          // 4*16*64*1024 = 4194304
constexpr size_t OFF_SM    = OFF_C2O + 4194304;         // 4*16*2*4096 = 524288
constexpr size_t WS_FLOATS = OFF_SM + 524288;           // ~116.5 MB

constexpr size_t OUT_LS  = 128;
constexpr size_t OUT_ASC = 128 + (size_t)LNUM*BNUM*2*IMG*IMG;

// ---------------- weight prep: transposes + deconv2*conv3 folding ----------------
__global__ void k_wprep(const float* __restrict__ c1w, const float* __restrict__ c2w,
                        const float* __restrict__ c3w, const float* __restrict__ c3b,
                        const float* __restrict__ ct2w, const float* __restrict__ ct2b,
                        float* __restrict__ ws) {
  int g = blockIdx.x * 256 + threadIdx.x;
  if (g < 884736) {
    // wt1[tap][ci][co] = conv1_w[co][ci][tap]
    int co = g & 127; int r = g >> 7; int ci = r % 768; int tap = r / 768;
    ws[OFF_WT1 + g] = c1w[((size_t)co * 768 + ci) * 9 + tap];
  } else if (g < 884736 + 73728) {
    int g2 = g - 884736;
    int co = g2 & 63; int r = g2 >> 6; int ci = r % 128; int tap = r / 128;
    ws[OFF_WT2 + g2] = c2w[((size_t)co * 128 + ci) * 9 + tap];
  } else if (g < 884736 + 73728 + 512) {
    // W23[c][c2][ab] = sum_o conv3_w[c2][o] * ct2_w[c][o][ab]
    int g3 = g - (884736 + 73728);
    int c = g3 >> 3, n = g3 & 7, c2 = n >> 2, ab = n & 3;
    float s = 0.f;
    for (int o = 0; o < 64; ++o) s += c3w[c2 * 64 + o] * ct2w[((size_t)c * 64 + o) * 4 + ab];
    ws[OFF_W23 + g3] = s;
  } else if (g < 884736 + 73728 + 514) {
    int c2 = g - (884736 + 73728 + 512);
    float s = c3b[c2];
    for (int o = 0; o < 64; ++o) s += c3w[c2 * 64 + o] * ct2b[o];
    ws[OFF_B23 + c2] = s;
  }
}

// ---------------- per-row inverse L2 norms ----------------
__global__ void k_rownorm(const float* __restrict__ qp, const float* __restrict__ pp,
                          float* __restrict__ inv_q, float* __restrict__ inv_p) {
  int wid = blockIdx.x * 4 + (threadIdx.x >> 6);
  int lane = threadIdx.x & 63;
  const int NQ = LNUM * BNUM * 256;
  const float* src; float* dst;
  if (wid < NQ) {
    int r = wid & 255, lb = wid >> 8;
    src = qp + ((size_t)lb * P1 + (r + 1)) * DNUM;
    dst = inv_q + wid;
  } else {
    int w2 = wid - NQ;
    int k = w2 & 2047, lb = w2 >> 11;
    int kp = k >> 8, r = k & 255;
    src = pp + (((size_t)lb * KPN + kp) * P1 + (r + 1)) * DNUM;
    dst = inv_p + w2;
  }
  float ss = 0.f;
  const float4* s4 = (const float4*)src;
  for (int i = lane; i < DNUM / 4; i += 64) {
    float4 v = s4[i];
    ss += v.x * v.x + v.y * v.y + v.z * v.z + v.w * v.w;
  }
  #pragma unroll
  for (int o = 32; o; o >>= 1) ss += __shfl_down(ss, o);
  if (lane == 0) {
    float n = fmaxf(sqrtf(ss), 1e-12f);
    *dst = 1.f / n;
  }
}

// ---------------- fused cost GEMM + min/argmin ----------------
// block: (qt, b, l); 32 q rows x all 2048 k. 256 thr = 8 tq x 32 tk; thread tile 4q x 8k.
__global__ __launch_bounds__(256) void k_cost(
    const float* __restrict__ qp, const float* __restrict__ pp,
    const float* __restrict__ inv_q, const float* __restrict__ inv_p,
    float* __restrict__ align_out, int* __restrict__ idx_out) {
  __shared__ float qs[32 * 32];
  __shared__ float ps[256 * 32];
  __shared__ float redv[32][33];
  __shared__ int   redi[32][33];
  int qt = blockIdx.x, b = blockIdx.y, l = blockIdx.z;
  int lb = l * BNUM + b;
  int t = threadIdx.x;
  int tq = t >> 5, tk = t & 31;
  const float* qbase = qp + ((size_t)lb * P1 + 1 + qt * 32) * DNUM;

  float rb[4]; int ri[4];
  #pragma unroll
  for (int i = 0; i < 4; ++i) { rb[i] = -FLT_MAX; ri[i] = 0; }

  for (int kt = 0; kt < NK; kt += 256) {
    float acc[4][8];
    #pragma unroll
    for (int i = 0; i < 4; ++i)
      #pragma unroll
      for (int j = 0; j < 8; ++j) acc[i][j] = 0.f;

    for (int kc = 0; kc < DNUM; kc += 32) {
      { // stage q 32x32
        int r = t >> 3, c4 = t & 7;
        float4 v = *(const float4*)(qbase + (size_t)r * DNUM + kc + c4 * 4);
        *(float4*)(qs + r * 32 + c4 * 4) = v;
      }
      // stage p 256x32, XOR-swizzled
      #pragma unroll
      for (int it = 0; it < 8; ++it) {
        int r = it * 32 + (t >> 3), c4 = t & 7;
        int k = kt + r;
        const float* prow = pp + (((size_t)lb * KPN + (k >> 8)) * P1 + 1 + (k & 255)) * DNUM;
        float4 v = *(const float4*)(prow + kc + c4 * 4);
        *(float4*)(ps + r * 32 + ((c4 ^ (r & 7)) << 2)) = v;
      }
      __syncthreads();
      #pragma unroll
      for (int kk4 = 0; kk4 < 8; ++kk4) {
        float4 qv[4];
        #pragma unroll
        for (int i = 0; i < 4; ++i)
          qv[i] = *(const float4*)(qs + (tq * 4 + i) * 32 + kk4 * 4);
        #pragma unroll
        for (int j = 0; j < 8; ++j) {
          int r = tk + 32 * j;
          float4 pv = *(const float4*)(ps + r * 32 + ((kk4 ^ (r & 7)) << 2));
          #pragma unroll
          for (int i = 0; i < 4; ++i) {
            acc[i][j] += qv[i].x * pv.x;
            acc[i][j] += qv[i].y * pv.y;
            acc[i][j] += qv[i].z * pv.z;
            acc[i][j] += qv[i].w * pv.w;
          }
        }
      }
      __syncthreads();
    }
    // fold into running best (sim = dot * inv_p; inv_q applied at the end)
    #pragma unroll
    for (int j = 0; j < 8; ++j) {
      int k = kt + tk + 32 * j;
      float ip = inv_p[(size_t)lb * NK + k];
      #pragma unroll
      for (int i = 0; i < 4; ++i) {
        float v = acc[i][j] * ip;
        if (v > rb[i]) { rb[i] = v; ri[i] = k; }
      }
    }
  }
  #pragma unroll
  for (int i = 0; i < 4; ++i) { redv[tq * 4 + i][tk] = rb[i]; redi[tq * 4 + i][tk] = ri[i]; }
  __syncthreads();
  if (t < 32) {
    float bv = redv[t][0]; int bi = redi[t][0];
    for (int j = 1; j < 32; ++j) {
      float v = redv[t][j]; int ii = redi[t][j];
      if (v > bv || (v == bv && ii < bi)) { bv = v; bi = ii; }
    }
    int q = qt * 32 + t;
    float iq = inv_q[(size_t)lb * HW1 + q];
    align_out[(size_t)lb * HW1 + q] = 1.f - iq * bv;
    idx_out[(size_t)lb * HW1 + q] = bi;
  }
}

// ---------------- fusion = q_n + |q_n - aligned_n|, NCHW, + BN partial sums ----------------
__global__ void k_fusion(const float* __restrict__ qp, const float* __restrict__ pp,
                         const float* __restrict__ inv_q, const float* __restrict__ inv_p,
                         const int* __restrict__ idx_ws, float* __restrict__ fus,
                         float* __restrict__ partA) {
  __shared__ float tile[32][37];
  __shared__ float s_iq[HW1], s_ip[HW1];
  __shared__ int   s_id[HW1];
  int b = blockIdx.x, l = blockIdx.y;
  int lb = l * BNUM + b;
  int t = threadIdx.x;
  s_iq[t] = inv_q[(size_t)lb * HW1 + t];
  int id0 = idx_ws[(size_t)lb * HW1 + t];
  s_id[t] = id0;
  s_ip[t] = inv_p[(size_t)lb * NK + id0];
  __syncthreads();
  int hi = t >> 3, c4 = t & 7;   // phase A: 32 hw x 8 float4 (32 d)
  int di = t >> 3, h4 = t & 7;   // phase B: 32 d x 8 float4 (32 hw)
  for (int dc = 0; dc < DNUM; dc += 32) {
    float s = 0.f, ss = 0.f;
    for (int hb = 0; hb < HW1; hb += 32) {
      { // phase A
        int hw = hb + hi;
        const float* qrow = qp + ((size_t)lb * P1 + 1 + hw) * DNUM + dc;
        int ii = s_id[hw];
        const float* prow = pp + (((size_t)lb * KPN + (ii >> 8)) * P1 + 1 + (ii & 255)) * DNUM + dc;
        float iq = s_iq[hw], ip = s_ip[hw];
        float4 qv = *(const float4*)(qrow + c4 * 4);
        float4 pv = *(const float4*)(prow + c4 * 4);
        float f0 = qv.x * iq; f0 = f0 + fabsf(f0 - pv.x * ip);
        float f1 = qv.y * iq; f1 = f1 + fabsf(f1 - pv.y * ip);
        float f2 = qv.z * iq; f2 = f2 + fabsf(f2 - pv.z * ip);
        float f3 = qv.w * iq; f3 = f3 + fabsf(f3 - pv.w * ip);
        tile[hi][c4 * 4 + 0] = f0; tile[hi][c4 * 4 + 1] = f1;
        tile[hi][c4 * 4 + 2] = f2; tile[hi][c4 * 4 + 3] = f3;
      }
      __syncthreads();
      { // phase B (transposed write, coalesced over hw)
        float v0 = tile[h4 * 4 + 0][di];
        float v1 = tile[h4 * 4 + 1][di];
        float v2 = tile[h4 * 4 + 2][di];
        float v3 = tile[h4 * 4 + 3][di];
        float4 o; o.x = v0; o.y = v1; o.z = v2; o.w = v3;
        *(float4*)(fus + ((size_t)lb * DNUM + dc + di) * HW1 + hb + h4 * 4) = o;
        s += v0 + v1 + v2 + v3;
        ss += v0 * v0 + v1 * v1 + v2 * v2 + v3 * v3;
      }
      __syncthreads();
    }
    #pragma unroll
    for (int o = 4; o; o >>= 1) { s += __shfl_down(s, o, 8); ss += __shfl_down(ss, o, 8); }
    if (h4 == 0) {
      int d = dc + di;
      partA[(((size_t)l * DNUM + d) * BNUM + b) * 2 + 0] = s;
      partA[(((size_t)l * DNUM + d) * BNUM + b) * 2 + 1] = ss;
    }
  }
}

// ---------------- BN stats finalize: parts[l][C][nparts][2] -> scale/shift[l][C] ----------------
__global__ void k_bn_final(const float* __restrict__ part, int nparts, int C, float cnt,
                           const float* __restrict__ gamma, const float* __restrict__ beta,
                           int per_layer_gb, float* __restrict__ scale, float* __restrict__ shift) {
  int i = blockIdx.x * 256 + threadIdx.x;
  if (i >= LNUM * C) return;
  int c = i % C;
  float s = 0.f, ss = 0.f;
  const float* p = part + (size_t)i * nparts * 2;
  for (int j = 0; j < nparts; ++j) { s += p[j * 2]; ss += p[j * 2 + 1]; }
  float mean = s / cnt, var = ss / cnt - mean * mean;
  float g = gamma[per_layer_gb ? i : c], bb = beta[per_layer_gb ? i : c];
  float sc = g * rsqrtf(var + 1e-5f);
  scale[i] = sc; shift[i] = bb - mean * sc;
}

// ---------------- conv1 v2: 768->128 3x3 SAME on 16x16 ----------------
// Stage 16-ci input chunk ONCE (BN applied), all 9 taps from LDS.
// Thread tile: 4 co x 8 strided pos (pos = tpos + 32j) -> conflict-free b32 LDS reads.
__global__ __launch_bounds__(256) void k_conv1(
    const float* __restrict__ fus, const float* __restrict__ scA, const float* __restrict__ shA,
    const float* __restrict__ wt1, float* __restrict__ out1, float* __restrict__ part1) {
  __shared__ float ins[16 * 260];      // 16 ci x 256 pos (stride 260; col 256 = zero pad)
  __shared__ float wsm[9 * 16 * 32];   // [tap][ci][co32]
  int cog = blockIdx.x, b = blockIdx.y, l = blockIdx.z;
  int lb = l * BNUM + b;
  int t = threadIdx.x;
  int tco = t >> 5, tpos = t & 31;
  const float* fin = fus + (size_t)lb * DNUM * HW1;
  float acc[4][8];
  #pragma unroll
  for (int i = 0; i < 4; ++i)
    #pragma unroll
    for (int j = 0; j < 8; ++j) acc[i][j] = 0.f;

  if (t < 16) {  // zero column (absorbs SAME padding via address select)
    ins[t * 260 + 256] = 0.f; ins[t * 260 + 257] = 0.f;
    ins[t * 260 + 258] = 0.f; ins[t * 260 + 259] = 0.f;
  }

  for (int cc = 0; cc < DNUM; cc += 16) {
    // stage input 16 x 256 (BN on load): 1024 f4, 4 per thread
    #pragma unroll
    for (int it = 0; it < 4; ++it) {
      int idx = it * 256 + t;
      int row = idx >> 6, f4 = idx & 63;
      float sc = scA[l * DNUM + cc + row], sh = shA[l * DNUM + cc + row];
      float4 v = *(const float4*)(fin + (size_t)(cc + row) * HW1 + f4 * 4);
      v.x = v.x * sc + sh; v.y = v.y * sc + sh; v.z = v.z * sc + sh; v.w = v.w * sc + sh;
      *(float4*)(ins + row * 260 + f4 * 4) = v;
    }
    // stage weights for all 9 taps: 9*16*32 = 4608 floats = 1152 f4
    #pragma unroll
    for (int it = 0; it < 5; ++it) {
      int idx = it * 256 + t;
      if (idx < 1152) {
        int row = idx >> 3, f4c = idx & 7;   // row = tap*16+ci
        int tap = row >> 4, ci = row & 15;
        *(float4*)(wsm + row * 32 + f4c * 4) =
            *(const float4*)(wt1 + ((size_t)tap * DNUM + cc + ci) * MID + cog * 32 + f4c * 4);
      }
    }
    __syncthreads();
    for (int tap = 0; tap < 9; ++tap) {
      int ky = tap / 3 - 1, kx = tap % 3 - 1;
      int off[8];
      #pragma unroll
      for (int j = 0; j < 8; ++j) {
        int pos = tpos + 32 * j;
        int y = (pos >> 4) + ky, x = (pos & 15) + kx;
        off[j] = (((unsigned)y < 16u) && ((unsigned)x < 16u)) ? y * 16 + x : 256;
      }
      const float* wbase = wsm + tap * 16 * 32 + tco * 4;
      #pragma unroll
      for (int ci = 0; ci < 16; ++ci) {
        float4 wv = *(const float4*)(wbase + ci * 32);   // wave-broadcast
        float xv[8];
        #pragma unroll
        for (int j = 0; j < 8; ++j) xv[j] = ins[ci * 260 + off[j]];  // lane-consecutive b32
        float wa[4] = {wv.x, wv.y, wv.z, wv.w};
        #pragma unroll
        for (int i = 0; i < 4; ++i)
          #pragma unroll
          for (int j = 0; j < 8; ++j) acc[i][j] = fmaf(wa[i], xv[j], acc[i][j]);
      }
    }
    __syncthreads();
  }
  int co0 = cog * 32 + tco * 4;
  #pragma unroll
  for (int i = 0; i < 4; ++i) {
    float s = 0.f, ssum = 0.f;
    #pragma unroll
    for (int j = 0; j < 8; ++j) { s += acc[i][j]; ssum += acc[i][j] * acc[i][j]; }
    #pragma unroll
    for (int o = 16; o; o >>= 1) { s += __shfl_down(s, o, 32); ssum += __shfl_down(ssum, o, 32); }
    if (tpos == 0) {
      part1[(((size_t)l * MID + co0 + i) * BNUM + b) * 2 + 0] = s;
      part1[(((size_t)l * MID + co0 + i) * BNUM + b) * 2 + 1] = ssum;
    }
    #pragma unroll
    for (int j = 0; j < 8; ++j)
      out1[((size_t)lb * MID + co0 + i) * HW1 + tpos + 32 * j] = acc[i][j];
  }
}

// ---------------- deconv1 (ct1): GEMM over n = o*4+ab, bn1+relu applied on load ----------------
__global__ __launch_bounds__(256) void k_deconv1(
    const float* __restrict__ out1, const float* __restrict__ sc1, const float* __restrict__ sh1,
    const float* __restrict__ ct1w, const float* __restrict__ ct1b, float* __restrict__ h1) {
  __shared__ float xs[32 * 64];
  __shared__ float wds[32 * 64];
  int ng = blockIdx.x >> 2, pg = blockIdx.x & 3;
  int b = blockIdx.y, l = blockIdx.z;
  int lb = l * BNUM + b;
  int t = threadIdx.x;
  int tn = t >> 4, tp = t & 15;
  float acc[4][4];
  #pragma unroll
  for (int i = 0; i < 4; ++i)
    #pragma unroll
    for (int j = 0; j < 4; ++j) acc[i][j] = 0.f;

  for (int cc = 0; cc < MID; cc += 32) {
    #pragma unroll
    for (int it = 0; it < 8; ++it) {
      int ii = it * 256 + t;
      int ci = ii >> 6, p = ii & 63;
      int c = cc + ci;
      float raw = out1[((size_t)lb * MID + c) * HW1 + pg * 64 + p];
      xs[ci * 64 + p] = fmaxf(raw * sc1[l * MID + c] + sh1[l * MID + c], 0.f);
    }
    #pragma unroll
    for (int it = 0; it < 2; ++it) {
      int ii = it * 256 + t;
      int ci = ii >> 4, n4 = ii & 15;
      *(float4*)(wds + ci * 64 + n4 * 4) =
          *(const float4*)(ct1w + ((size_t)(cc + ci)) * 512 + ng * 64 + n4 * 4);
    }
    __syncthreads();
    #pragma unroll
    for (int ci = 0; ci < 32; ++ci) {
      float4 wv = *(const float4*)(wds + ci * 64 + tn * 4);
      float4 xv = *(const float4*)(xs + ci * 64 + tp * 4);
      float wa[4] = {wv.x, wv.y, wv.z, wv.w};
      float xa[4] = {xv.x, xv.y, xv.z, xv.w};
      #pragma unroll
      for (int i = 0; i < 4; ++i)
        #pragma unroll
        for (int j = 0; j < 4; ++j) acc[i][j] += wa[i] * xa[j];
    }
    __syncthreads();
  }
  #pragma unroll
  for (int i = 0; i < 4; ++i) {
    int n = ng * 64 + tn * 4 + i;
    int o = n >> 2, ab = n & 3, a = ab >> 1, bb = ab & 1;
    float bias = ct1b[o];
    #pragma unroll
    for (int j = 0; j < 4; ++j) {
      int p = pg * 64 + tp * 4 + j;
      int y = p >> 4, x = p & 15;
      h1[((size_t)lb * MID + o) * HW2 + (2 * y + a) * 32 + (2 * x + bb)] = acc[i][j] + bias;
    }
  }
}

// ---------------- conv2 v2: 128->64 3x3 SAME on 32x32 ----------------
// Block: posg (8 image rows). Stage 16-ci chunk with row halo ONCE; 9 taps from LDS.
// Thread tile: 8 co x 8 pos (pos row j, col tpos) -> conflict-free b32 reads.
__global__ __launch_bounds__(256) void k_conv2(
    const float* __restrict__ h1, const float* __restrict__ wt2,
    float* __restrict__ out2, float* __restrict__ part2) {
  __shared__ float ins2[16 * 360];      // 16 ci x 10 rows x 36 (cols 32..35 zero pad)
  __shared__ float wsm2[9 * 16 * 64];   // [tap][ci][co64]
  int posg = blockIdx.x, b = blockIdx.y, l = blockIdx.z;
  int lb = l * BNUM + b;
  int t = threadIdx.x;
  int tco = t >> 5, tpos = t & 31;
  float acc[8][8];
  #pragma unroll
  for (int i = 0; i < 8; ++i)
    #pragma unroll
    for (int j = 0; j < 8; ++j) acc[i][j] = 0.f;

  if (t < 160) {  // zero x-pad columns
    int ci = t / 10, r = t % 10;
    ins2[ci * 360 + r * 36 + 32] = 0.f; ins2[ci * 360 + r * 36 + 33] = 0.f;
    ins2[ci * 360 + r * 36 + 34] = 0.f; ins2[ci * 360 + r * 36 + 35] = 0.f;
  }

  for (int cc = 0; cc < MID; cc += 16) {
    // stage input: 16 ci x 10 rows x 32 cols = 1280 f4, 5 per thread
    #pragma unroll
    for (int it = 0; it < 5; ++it) {
      int idx = it * 256 + t;
      int ci = idx / 80, rem = idx - ci * 80;
      int r = rem >> 3, f4 = rem & 7;
      int gy = posg * 8 - 1 + r;
      float4 v;
      if ((unsigned)gy < 32u)
        v = *(const float4*)(h1 + ((size_t)lb * MID + cc + ci) * HW2 + gy * 32 + f4 * 4);
      else { v.x = 0.f; v.y = 0.f; v.z = 0.f; v.w = 0.f; }
      *(float4*)(ins2 + ci * 360 + r * 36 + f4 * 4) = v;
    }
    // stage weights: 9*16*64 = 9216 floats = 2304 f4, 9 per thread
    #pragma unroll
    for (int it = 0; it < 9; ++it) {
      int idx = it * 256 + t;
      int row = idx >> 4, f4c = idx & 15;   // row = tap*16+ci
      int tap = row >> 4, ci = row & 15;
      *(float4*)(wsm2 + row * 64 + f4c * 4) =
          *(const float4*)(wt2 + ((size_t)tap * MID + cc + ci) * MID2 + f4c * 4);
    }
    __syncthreads();
    for (int tap = 0; tap < 9; ++tap) {
      int ky = tap / 3 - 1, kx = tap % 3 - 1;
      int colsel = tpos + kx;
      if ((unsigned)colsel >= 32u) colsel = 33;  // zero pad col
      int off[8];
      #pragma unroll
      for (int j = 0; j < 8; ++j) off[j] = (1 + j + ky) * 36 + colsel;
      const float* wbase = wsm2 + tap * 16 * 64 + tco * 8;
      #pragma unroll
      for (int ci = 0; ci < 16; ++ci) {
        float4 w0 = *(const float4*)(wbase + ci * 64);
        float4 w1 = *(const float4*)(wbase + ci * 64 + 4);
        float xv[8];
        #pragma unroll
        for (int j = 0; j < 8; ++j) xv[j] = ins2[ci * 360 + off[j]];
        float wa[8] = {w0.x, w0.y, w0.z, w0.w, w1.x, w1.y, w1.z, w1.w};
        #pragma unroll
        for (int i = 0; i < 8; ++i)
          #pragma unroll
          for (int j = 0; j < 8; ++j) acc[i][j] = fmaf(wa[i], xv[j], acc[i][j]);
      }
    }
    __syncthreads();
  }
  int co0 = tco * 8;
  #pragma unroll
  for (int i = 0; i < 8; ++i) {
    float s = 0.f, ssum = 0.f;
    #pragma unroll
    for (int j = 0; j < 8; ++j) { s += acc[i][j]; ssum += acc[i][j] * acc[i][j]; }
    #pragma unroll
    for (int o = 16; o; o >>= 1) { s += __shfl_down(s, o, 32); ssum += __shfl_down(ssum, o, 32); }
    if (tpos == 0) {
      part2[(((size_t)l * MID2 + co0 + i) * 64 + (b * 4 + posg)) * 2 + 0] = s;
      part2[(((size_t)l * MID2 + co0 + i) * 64 + (b * 4 + posg)) * 2 + 1] = ssum;
    }
    #pragma unroll
    for (int j = 0; j < 8; ++j)
      out2[((size_t)lb * MID2 + co0 + i) * HW2 + (posg * 8 + j) * 32 + tpos] = acc[i][j];
  }
}

// ---------------- fused deconv2+conv3+softmax (bn2+relu on load) ----------------
__global__ void k_dc2c3sm(const float* __restrict__ out2, const float* __restrict__ sc2,
                          const float* __restrict__ sh2, const float* __restrict__ wsW23,
                          const float* __restrict__ wsB23, float* __restrict__ sm) {
  __shared__ float w23[64 * 8];
  __shared__ float b23s[2];
  __shared__ float ssc[64], ssh[64];
  int b = blockIdx.x, l = blockIdx.y;
  int lb = l * BNUM + b;
  int t = threadIdx.x;
  w23[t] = wsW23[t];
  w23[t + 256] = wsW23[t + 256];
  if (t < 2) b23s[t] = wsB23[t];
  if (t < 64) { ssc[t] = sc2[l * MID2 + t]; ssh[t] = sh2[l * MID2 + t]; }
  __syncthreads();
  for (int it = 0; it < 4; ++it) {
    int p = it * 256 + t;
    float a[8];
    #pragma unroll
    for (int n = 0; n < 8; ++n) a[n] = 0.f;
    for (int c = 0; c < 64; ++c) {
      float v = fmaxf(out2[((size_t)lb * MID2 + c) * HW2 + p] * ssc[c] + ssh[c], 0.f);
      #pragma unroll
      for (int n = 0; n < 8; ++n) a[n] += v * w23[c * 8 + n];
    }
    int y = p >> 5, x = p & 31;
    #pragma unroll
    for (int ab = 0; ab < 4; ++ab) {
      float v0 = a[ab] + b23s[0];
      float v1 = a[4 + ab] + b23s[1];
      float m = fmaxf(v0, v1);
      float e0 = expf(v0 - m), e1 = expf(v1 - m);
      float inv = 1.f / (e0 + e1);
      int aa = ab >> 1, bb = ab & 1;
      int op = (2 * y + aa) * 64 + 2 * x + bb;
      sm[((size_t)lb * 2 + 0) * HW3 + op] = e0 * inv;
      sm[((size_t)lb * 2 + 1) * HW3 + op] = e1 * inv;
    }
  }
}

// ---------------- bilinear resize SxS -> 224x224 ----------------
template <int S>
__global__ void k_resize(const float* __restrict__ in, float* __restrict__ out, int total) {
  int gid = blockIdx.x * 256 + threadIdx.x;
  if (gid >= total) return;
  int m = gid / (IMG * IMG);
  int r = gid - m * (IMG * IMG);
  int oy = r / IMG, ox = r - oy * IMG;
  const float scale = (float)S / (float)IMG;
  float fy = ((float)oy + 0.5f) * scale - 0.5f;
  float fx = ((float)ox + 0.5f) * scale - 0.5f;
  float y0f = floorf(fy), x0f = floorf(fx);
  float wy = fy - y0f, wx = fx - x0f;
  int y0 = (int)y0f, x0 = (int)x0f;
  int y1 = y0 + 1, x1 = x0 + 1;
  y0 = min(max(y0, 0), S - 1); y1 = min(max(y1, 0), S - 1);
  x0 = min(max(x0, 0), S - 1); x1 = min(max(x1, 0), S - 1);
  const float* src = in + (size_t)m * S * S;
  float v00 = src[y0 * S + x0], v01 = src[y0 * S + x1];
  float v10 = src[y1 * S + x0], v11 = src[y1 * S + x1];
  out[gid] = (1.f - wy) * ((1.f - wx) * v00 + wx * v01) + wy * ((1.f - wx) * v10 + wx * v11);
}

// ---------------- pooled = (mean + top10mean)/2 over post-BN fusion rows ----------------
__global__ void k_pooled(const float* __restrict__ fus, const float* __restrict__ scA,
                         const float* __restrict__ shA, float* __restrict__ pooled) {
  int gid = blockIdx.x * 256 + threadIdx.x;
  if (gid >= LNUM * BNUM * DNUM) return;
  int lb = gid / DNUM, d = gid - lb * DNUM;
  int l = lb >> 4;
  float sc = scA[l * DNUM + d], sh = shA[l * DNUM + d];
  const float4* row = (const float4*)(fus + (size_t)gid * HW1);
  float top[10];
  #pragma unroll
  for (int i = 0; i < 10; ++i) top[i] = -FLT_MAX;
  float sum = 0.f;
  for (int c = 0; c < HW1 / 4; ++c) {
    float4 v4 = row[c];
    float vals[4] = {v4.x, v4.y, v4.z, v4.w};
    #pragma unroll
    for (int u = 0; u < 4; ++u) {
      float v = vals[u] * sc + sh;
      sum += v;
      if (v > top[9]) {
        top[9] = v;
        #pragma unroll
        for (int q = 9; q > 0; --q) {
          if (top[q] > top[q - 1]) { float tmp = top[q - 1]; top[q - 1] = top[q]; top[q] = tmp; }
        }
      }
    }
  }
  float t10 = 0.f;
  #pragma unroll
  for (int i = 0; i < 10; ++i) t10 += top[i];
  pooled[gid] = 0.5f * (sum * (1.f / 256.f) + t10 * 0.1f);
}

// ---------------- global head ----------------
__global__ void k_head(const float* __restrict__ pooled,
                       const float* __restrict__ g1w, const float* __restrict__ gbn1g,
                       const float* __restrict__ gbn1b, const float* __restrict__ g2w,
                       const float* __restrict__ gbn2g, const float* __restrict__ gbn2b,
                       const float* __restrict__ g3w, float* __restrict__ outgl) {
  __shared__ float g1o[16 * 128];
  __shared__ float g2o[16 * 64];
  __shared__ float ssc[128], ssh[128];
  int l = blockIdx.x;
  int t = threadIdx.x;
  const float* pl = pooled + (size_t)l * BNUM * DNUM;
  for (int it = 0; it < 8; ++it) {
    int id = it * 256 + t;
    int b = id >> 7, j = id & 127;
    const float* pr = pl + (size_t)b * DNUM;
    const float* wr = g1w + (size_t)j * DNUM;
    float s = 0.f;
    for (int k = 0; k < DNUM; k += 4)
      s += pr[k] * wr[k] + pr[k + 1] * wr[k + 1] + pr[k + 2] * wr[k + 2] + pr[k + 3] * wr[k + 3];
    g1o[b * 128 + j] = s;
  }
  __syncthreads();
  if (t < 128) {
    float s = 0.f, ss = 0.f;
    for (int b = 0; b < 16; ++b) { float v = g1o[b * 128 + t]; s += v; ss += v * v; }
    float m = s * (1.f / 16.f), var = ss * (1.f / 16.f) - m * m;
    float sc = gbn1g[t] * rsqrtf(var + 1e-5f);
    ssc[t] = sc; ssh[t] = gbn1b[t] - m * sc;
  }
  __syncthreads();
  for (int it = 0; it < 8; ++it) {
    int id = it * 256 + t;
    int b = id >> 7, j = id & 127;
    g1o[b * 128 + j] = fmaxf(g1o[b * 128 + j] * ssc[j] + ssh[j], 0.f);
  }
  __syncthreads();
  for (int it = 0; it < 4; ++it) {
    int id = it * 256 + t;
    int b = id >> 6, j = id & 63;
    const float* wr = g2w + (size_t)j * 128;
    float s = 0.f;
    for (int k = 0; k < 128; ++k) s += g1o[b * 128 + k] * wr[k];
    g2o[b * 64 + j] = s;
  }
  __syncthreads();
  if (t < 64) {
    float s = 0.f, ss = 0.f;
    for (int b = 0; b < 16; ++b) { float v = g2o[b * 64 + t]; s += v; ss += v * v; }
    float m = s * (1.f / 16.f), var = ss * (1.f / 16.f) - m * m;
    float sc = gbn2g[t] * rsqrtf(var + 1e-5f);
    ssc[t] = sc; ssh[t] = gbn2b[t] - m * sc;
  }
  __syncthreads();
  for (int it = 0; it < 4; ++it) {
    int id = it * 256 + t;
    int b = id >> 6, j = id & 63;
    g2o[b * 64 + j] = fmaxf(g2o[b * 64 + j] * ssc[j] + ssh[j], 0.f);
  }
  __syncthreads();
  if (t < 32) {
    int b = t >> 1, c = t & 1;
    const float* wr = g3w + (size_t)c * 64;
    float s = 0.f;
    for (int k = 0; k < 64; ++k) s += g2o[b * 64 + k] * wr[k];
    outgl[((size_t)l * BNUM + b) * 2 + c] = s;
  }
}

// ---------------- launch ----------------
extern "C" void kernel_launch(void* const* d_in, const int* in_sizes, int n_in,
                              void* d_out, int out_size, void* d_ws, size_t ws_size,
                              hipStream_t stream) {
  (void)in_sizes; (void)n_in; (void)out_size;
  if (ws_size < WS_FLOATS * sizeof(float)) return;

  const float* qp    = (const float*)d_in[1];
  const float* pp    = (const float*)d_in[3];
  const float* sbg   = (const float*)d_in[4];
  const float* sbb   = (const float*)d_in[5];
  const float* c1w   = (const float*)d_in[6];
  const float* bn1g  = (const float*)d_in[7];
  const float* bn1b  = (const float*)d_in[8];
  const float* ct1w  = (const float*)d_in[9];
  const float* ct1b  = (const float*)d_in[10];
  const float* c2w   = (const float*)d_in[11];
  const float* bn2g  = (const float*)d_in[12];
  const float* bn2b  = (const float*)d_in[13];
  const float* ct2w  = (const float*)d_in[14];
  const float* ct2b  = (const float*)d_in[15];
  const float* c3w   = (const float*)d_in[16];
  const float* c3b   = (const float*)d_in[17];
  const float* g1w   = (const float*)d_in[18];
  const float* gbn1g = (const float*)d_in[19];
  const float* gbn1b = (const float*)d_in[20];
  const float* g2w   = (const float*)d_in[21];
  const float* gbn2g = (const float*)d_in[22];
  const float* gbn2b = (const float*)d_in[23];
  const float* g3w   = (const float*)d_in[24];

  float* ws = (float*)d_ws;
  float* out = (float*)d_out;

  float* invq  = ws + OFF_INVQ;
  float* invp  = ws + OFF_INVP;
  float* alignb = ws + OFF_ALIGN;
  int*   idxb  = (int*)(ws + OFF_IDX);
  float* partA = ws + OFF_PARTA;
  float* scA   = ws + OFF_SCA;
  float* shA   = ws + OFF_SHA;
  float* part1 = ws + OFF_PART1;
  float* sc1   = ws + OFF_SC1;
  float* sh1   = ws + OFF_SH1;
  float* part2 = ws + OFF_PART2;
  float* sc2   = ws + OFF_SC2;
  float* sh2   = ws + OFF_SH2;
  float* poolb = ws + OFF_POOL;
  float* fusb  = ws + OFF_FUS;
  float* c1o   = ws + OFF_C1O;
  float* h1b   = ws + OFF_H1;
  float* c2o   = ws + OFF_C2O;
  float* smb   = ws + OFF_SM;
  float* wt1   = ws + OFF_WT1;
  float* wt2   = ws + OFF_WT2;

  k_wprep<<<(884736 + 73728 + 514 + 255) / 256, 256, 0, stream>>>(c1w, c2w, c3w, c3b, ct2w, ct2b, ws);
  k_rownorm<<<(LNUM * BNUM * (256 + 2048)) / 4, 256, 0, stream>>>(qp, pp, invq, invp);
  k_cost<<<dim3(8, BNUM, LNUM), 256, 0, stream>>>(qp, pp, invq, invp, alignb, idxb);
  k_fusion<<<dim3(BNUM, LNUM), 256, 0, stream>>>(qp, pp, invq, invp, idxb, fusb, partA);
  k_bn_final<<<(LNUM * DNUM + 255) / 256, 256, 0, stream>>>(partA, 16, DNUM, 4096.f, sbg, sbb, 1, scA, shA);
  k_conv1<<<dim3(4, BNUM, LNUM), 256, 0, stream>>>(fusb, scA, shA, wt1, c1o, part1);
  k_bn_final<<<(LNUM * MID + 255) / 256, 256, 0, stream>>>(part1, 16, MID, 4096.f, bn1g, bn1b, 0, sc1, sh1);
  k_deconv1<<<dim3(32, BNUM, LNUM), 256, 0, stream>>>(c1o, sc1, sh1, ct1w, ct1b, h1b);
  k_conv2<<<dim3(4, BNUM, LNUM), 256, 0, stream>>>(h1b, wt2, c2o, part2);
  k_bn_final<<<(LNUM * MID2 + 255) / 256, 256, 0, stream>>>(part2, 64, MID2, 16384.f, bn2g, bn2b, 0, sc2, sh2);
  k_dc2c3sm<<<dim3(BNUM, LNUM), 256, 0, stream>>>(c2o, sc2, sh2, ws + OFF_W23, ws + OFF_B23, smb);
  k_resize<64><<<(LNUM * BNUM * 2 * IMG * IMG + 255) / 256, 256, 0, stream>>>(smb, out + OUT_LS, LNUM * BNUM * 2 * IMG * IMG);
  k_resize<16><<<(LNUM * BNUM * IMG * IMG + 255) / 256, 256, 0, stream>>>(alignb, out + OUT_ASC, LNUM * BNUM * IMG * IMG);
  k_pooled<<<(LNUM * BNUM * DNUM + 255) / 256, 256, 0, stream>>>(fusb, scA, shA, poolb);
  k_head<<<LNUM, 256, 0, stream>>>(poolb, g1w, gbn1g, gbn1b, g2w, gbn2g, gbn2b, g3w, out);
}